// Round 1
// baseline (11330.546 us; speedup 1.0000x reference)
//
#include <hip/hip_runtime.h>
#include <stdint.h>

// MoleculeDecoder: greedy GRU decode, B=32, E=768, V=8192, T=256.
// Round 1: correctness-first multi-launch baseline.
//  - fp16 2-split (hi + 4096*residual) 3-pass MFMA => fp32-fidelity logits
//    (argmax must match reference trajectory exactly).
//  - per step: gates_k (GRU cell -> h_{t+1}) ; pred_k (logits, store, argmax).
//  - argmax via sortable u64 atomicMax, first-index tie-break (numpy semantics),
//    deterministic under any scheduling.

typedef unsigned long long u64;
typedef _Float16 f16;
using half8 = __attribute__((ext_vector_type(8))) _Float16;
using f32x4 = __attribute__((ext_vector_type(4))) float;

#define E_ 768
#define V_ 8192
#define T_ 256
#define HP 24576            // 32*768  (one h plane)
#define IH_PLANE (2304*768)
#define OUT_PLANE (8192*768)

__device__ __forceinline__ f32x4 mfma16(half8 a, half8 b, f32x4 c){
  return __builtin_amdgcn_mfma_f32_16x16x32_f16(a, b, c, 0, 0, 0);
}

// f = hi + lo/4096 + O(2^-24 * f); residual scaled by 4096 to stay fp16-normal.
__device__ __forceinline__ void split2(float f, f16& hi, f16& lo){
  f16 h = (f16)f;
  hi = h;
  lo = (f16)((f - (float)h) * 4096.0f);
}

// ---------------- prep: split weights to fp16 hi/lo planes; compute h0 ----------------
#define NB_CONV 1200
#define NB_H0   96
#define NG_IH   221184      // 2304*768/8
#define NG_ALL  1228800     // (2*2304 + 8192)*768/8

__global__ __launch_bounds__(256) void prep_k(
    const float* __restrict__ W_ih, const float* __restrict__ W_hh, const float* __restrict__ W_out,
    const float* __restrict__ latent, const float* __restrict__ W_lat, const float* __restrict__ b_lat,
    f16* __restrict__ Wih_s, f16* __restrict__ Whh_s, f16* __restrict__ Wout_s,
    float* __restrict__ h_f32, f16* __restrict__ h_s)
{
  int blk = blockIdx.x;
  if (blk < NB_CONV){
    for (int g = blk*256 + threadIdx.x; g < NG_ALL; g += NB_CONV*256){
      const float* src; f16* hi; f16* lo; int off;
      if (g < NG_IH)        { src=W_ih; hi=Wih_s; lo=Wih_s+IH_PLANE; off=g*8; }
      else if (g < 2*NG_IH) { src=W_hh; hi=Whh_s; lo=Whh_s+IH_PLANE; off=(g-NG_IH)*8; }
      else                  { src=W_out; hi=Wout_s; lo=Wout_s+OUT_PLANE; off=(g-2*NG_IH)*8; }
      float4 a = *(const float4*)(src+off);
      float4 b = *(const float4*)(src+off+4);
      float fs[8] = {a.x,a.y,a.z,a.w,b.x,b.y,b.z,b.w};
      half8 vh, vl;
      #pragma unroll
      for (int j=0;j<8;j++){ f16 h,l; split2(fs[j],h,l); vh[j]=h; vl[j]=l; }
      *(half8*)(hi+off) = vh;
      *(half8*)(lo+off) = vl;
    }
  } else {
    // h0 = latent @ W_lat^T + b_lat   (fp32), plus its fp16 hi/lo planes (parity 0)
    int tid = (blk-NB_CONV)*256 + threadIdx.x;     // 0..24575
    int b = tid/768, e = tid - b*768;
    const float4* wr = (const float4*)(W_lat + (size_t)e*768);
    const float4* xr = (const float4*)(latent + (size_t)b*768);
    float s0=0.f,s1=0.f,s2=0.f,s3=0.f;
    for (int k=0;k<192;k++){
      float4 w = wr[k]; float4 x = xr[k];
      s0 += w.x*x.x; s1 += w.y*x.y; s2 += w.z*x.z; s3 += w.w*x.w;
    }
    float acc = b_lat[e] + ((s0+s1)+(s2+s3));
    h_f32[b*768+e] = acc;
    f16 h,l; split2(acc,h,l);
    h_s[0*HP + b*768+e] = h;
    h_s[1*HP + b*768+e] = l;
  }
}

// ---------------- gates: (h_t, tok_t) -> h_{t+1}  [48 blocks x 512] ----------------
// Block owns e-block of 16. 8 waves = 2 m-tiles x 4 K-chunks. 6 MFMA chains:
// gi_{r,z,n} (A = emb[tok], split on the fly) and gh_{r,z,n} (A = h_s).
__global__ __launch_bounds__(512) void gates_k(int t,
    const float* __restrict__ emb, const float* __restrict__ b_ih, const float* __restrict__ b_hh,
    const f16* __restrict__ Wih_s, const f16* __restrict__ Whh_s,
    float* __restrict__ h_f32, f16* __restrict__ h_s, u64* __restrict__ slots)
{
  __shared__ float red[8][64][25];   // pad 25 to break bank conflicts
  const int pin = t & 1, pout = pin ^ 1;
  u64* slot_rd = slots + ((t+1)&1)*32;
  if (blockIdx.x==0 && threadIdx.x<32){
    slots[(t&1)*32 + threadIdx.x] = 0ull;          // reset slot pred_t will fill
    if (t==0) slot_rd[threadIdx.x] = 0ull;         // t=0: nobody reads it; init both
  }
  const int w = threadIdx.x>>6, lane = threadIdx.x&63;
  const int m = w>>2, kc = w&3;
  const int col = lane&15, kg = lane>>4;
  const int e0 = blockIdx.x*16;
  const int bA = m*16 + col;                       // A-operand row (batch)
  int tok = 1;                                     // <sos>
  if (t > 0){
    u64 key = slot_rd[bA];
    tok = (int)(0xFFFFFFFFu - (uint32_t)(key & 0xFFFFFFFFull));
  }
  // preload this lane's x = emb[tok] fragments for its K-chunk, split on the fly
  const float* xsrc = emb + (size_t)tok*768;
  half8 xh[6], xl[6];
  #pragma unroll
  for (int i=0;i<6;i++){
    int k0 = kc*192 + i*32 + kg*8;
    float4 a = *(const float4*)(xsrc+k0);
    float4 c = *(const float4*)(xsrc+k0+4);
    float fs[8] = {a.x,a.y,a.z,a.w,c.x,c.y,c.z,c.w};
    #pragma unroll
    for (int j=0;j<8;j++){ f16 h,l; split2(fs[j],h,l); xh[i][j]=h; xl[i][j]=l; }
  }
  f32x4 z4 = {0.f,0.f,0.f,0.f};
  f32x4 acc0[6], acc1[6];
  #pragma unroll
  for (int q=0;q<6;q++){ acc0[q]=z4; acc1[q]=z4; }
  const f16* hhi = h_s + (pin*2+0)*HP;
  const f16* hlo = h_s + (pin*2+1)*HP;
  for (int i=0;i<6;i++){
    const int k0 = kc*192 + i*32 + kg*8;
    half8 ah_h = *(const half8*)(hhi + bA*768 + k0);
    half8 al_h = *(const half8*)(hlo + bA*768 + k0);
    #pragma unroll
    for (int tt=0;tt<6;tt++){
      const f16* Wb = (tt<3)? Wih_s : Whh_s;
      const int row = (tt%3)*768 + e0 + col;       // B col = W row index
      half8 bh = *(const half8*)(Wb + (size_t)row*768 + k0);
      half8 bl = *(const half8*)(Wb + IH_PLANE + (size_t)row*768 + k0);
      half8 a_h = (tt<3)? xh[i] : ah_h;
      half8 a_l = (tt<3)? xl[i] : al_h;
      acc0[tt] = mfma16(a_h, bh, acc0[tt]);
      acc1[tt] = mfma16(a_h, bl, acc1[tt]);
      acc1[tt] = mfma16(a_l, bh, acc1[tt]);
    }
  }
  #pragma unroll
  for (int tt=0;tt<6;tt++)
    #pragma unroll
    for (int r=0;r<4;r++)
      red[w][lane][tt*4+r] = acc0[tt][r] + acc1[tt][r]*(1.0f/4096.0f);
  __syncthreads();
  if (kc==0){                                      // waves 0 and 4 finish their m-tile
    float v[24];
    #pragma unroll
    for (int q=0;q<24;q++)
      v[q] = red[w][lane][q] + red[w+1][lane][q] + red[w+2][lane][q] + red[w+3][lane][q];
    const int e = e0 + col;
    float bir=b_ih[e], biz=b_ih[768+e], bin_=b_ih[1536+e];
    float bhr=b_hh[e], bhz=b_hh[768+e], bhn=b_hh[1536+e];
    #pragma unroll
    for (int r=0;r<4;r++){
      int b = m*16 + kg*4 + r;                     // C/D row = (lane>>4)*4+reg (HW-verified)
      float gir=v[0+r]+bir,  giz=v[4+r]+biz,  gin=v[8+r]+bin_;
      float ghr=v[12+r]+bhr, ghz=v[16+r]+bhz, ghn=v[20+r]+bhn;
      float rr = 1.0f/(1.0f+expf(-(gir+ghr)));
      float zz = 1.0f/(1.0f+expf(-(giz+ghz)));
      float nn = tanhf(gin + rr*ghn);
      float hold = h_f32[pin*HP + b*768 + e];
      float hnew = (1.0f-zz)*nn + zz*hold;
      h_f32[pout*HP + b*768 + e] = hnew;
      f16 h,l; split2(hnew,h,l);
      h_s[(pout*2+0)*HP + b*768+e] = h;
      h_s[(pout*2+1)*HP + b*768+e] = l;
    }
  }
}

// ---------------- pred: logits + store + argmax  [256 blocks x 512] ----------------
// Block owns 32 vocab cols. 8 waves = 2 m-tiles x 2 n-tiles x 2 K-halves.
__global__ __launch_bounds__(512) void pred_k(int t,
    const f16* __restrict__ Wout_s, const f16* __restrict__ h_s,
    const float* __restrict__ b_out, float* __restrict__ out, u64* __restrict__ slots)
{
  __shared__ float redv[2][2][64][4];
  __shared__ float amv[32][2];
  __shared__ int   ami[32][2];
  const int ph = (t&1)^1;                          // parity of h_{t+1} (written by gates_t)
  const int w = threadIdx.x>>6, lane = threadIdx.x&63;
  const int m = w>>2, n = (w>>1)&1, kc = w&1;
  const int col = lane&15, kg = lane>>4;
  const int v0 = blockIdx.x*32 + n*16;
  const int bA = m*16 + col;
  const f16* hhi = h_s + (ph*2+0)*HP;
  const f16* hlo = h_s + (ph*2+1)*HP;
  const f16* wbh = Wout_s + (size_t)(v0+col)*768;
  const f16* wbl = Wout_s + OUT_PLANE + (size_t)(v0+col)*768;
  f32x4 acc0 = {0.f,0.f,0.f,0.f}, acc1 = {0.f,0.f,0.f,0.f};
  for (int i=0;i<12;i++){
    const int k0 = kc*384 + i*32 + kg*8;
    half8 ah = *(const half8*)(hhi + bA*768 + k0);
    half8 al = *(const half8*)(hlo + bA*768 + k0);
    half8 bh = *(const half8*)(wbh + k0);
    half8 bl = *(const half8*)(wbl + k0);
    acc0 = mfma16(ah,bh,acc0);
    acc1 = mfma16(ah,bl,acc1);
    acc1 = mfma16(al,bh,acc1);
  }
  float val[4];
  #pragma unroll
  for (int r=0;r<4;r++) val[r] = acc0[r] + acc1[r]*(1.0f/4096.0f);
  if (kc==1){
    #pragma unroll
    for (int r=0;r<4;r++) redv[m][n][lane][r] = val[r];
  }
  __syncthreads();
  if (kc==0){
    const int v = v0 + col;
    const float bo = b_out[v];
    const int b0 = m*16 + kg*4;
    float pv[4];
    #pragma unroll
    for (int r=0;r<4;r++){
      float p = val[r] + redv[m][n][lane][r] + bo;
      out[(size_t)(b0+r)*((size_t)T_*V_) + (size_t)t*V_ + v] = p;
      pv[r] = p;
    }
    // argmax over the 16 cols held by this lane group (first-index tie-break)
    #pragma unroll
    for (int r=0;r<4;r++){
      float vv = pv[r]; int ii = v;
      #pragma unroll
      for (int o=1;o<16;o<<=1){
        float v2 = __shfl_xor(vv,o);
        int   i2 = __shfl_xor(ii,o);
        if (v2>vv || (v2==vv && i2<ii)){ vv=v2; ii=i2; }
      }
      if (col==0){ amv[b0+r][n]=vv; ami[b0+r][n]=ii; }
    }
  }
  __syncthreads();
  if (threadIdx.x < 32){
    int b = threadIdx.x;
    float v1=amv[b][0]; int i1=ami[b][0];
    float v2=amv[b][1]; int i2=ami[b][1];
    if (v2>v1 || (v2==v1 && i2<i1)){ v1=v2; i1=i2; }
    uint32_t fb = __float_as_uint(v1);
    uint32_t s  = fb ^ ((uint32_t)((int32_t)fb>>31) | 0x80000000u);  // sortable float
    u64 key = ((u64)s<<32) | (u64)(0xFFFFFFFFu - (uint32_t)i1);      // ties -> smaller idx
    atomicMax(slots + (t&1)*32 + b, key);
  }
}

// ---------------- host ----------------
extern "C" void kernel_launch(void* const* d_in, const int* in_sizes, int n_in,
                              void* d_out, int out_size, void* d_ws, size_t ws_size,
                              hipStream_t stream){
  const float* latent = (const float*)d_in[0];
  const float* W_lat  = (const float*)d_in[1];
  const float* b_lat  = (const float*)d_in[2];
  const float* emb    = (const float*)d_in[3];
  const float* W_ih   = (const float*)d_in[4];
  const float* W_hh   = (const float*)d_in[5];
  const float* b_ih   = (const float*)d_in[6];
  const float* b_hh   = (const float*)d_in[7];
  const float* W_out  = (const float*)d_in[8];
  const float* b_out  = (const float*)d_in[9];
  float* out = (float*)d_out;
  (void)in_sizes; (void)n_in; (void)out_size; (void)ws_size;

  char* ws = (char*)d_ws;
  size_t off = 0;
  auto carve = [&](size_t bytes)->char*{
    char* p = ws + off; off += (bytes + 255) & ~(size_t)255; return p;
  };
  f16*   Wih_s  = (f16*)  carve((size_t)2*IH_PLANE*2);   //  7.08 MB
  f16*   Whh_s  = (f16*)  carve((size_t)2*IH_PLANE*2);   //  7.08 MB
  f16*   Wout_s = (f16*)  carve((size_t)2*OUT_PLANE*2);  // 25.17 MB
  float* h_f32  = (float*)carve((size_t)2*HP*4);         // h fp32, 2 parities
  f16*   h_s    = (f16*)  carve((size_t)4*HP*2);         // h hi/lo, 2 parities
  u64*   slots  = (u64*)  carve(64*8);                   // argmax slots, 2 parities
  // total ~39.7 MB of d_ws

  hipLaunchKernelGGL(prep_k, dim3(NB_CONV+NB_H0), dim3(256), 0, stream,
                     W_ih, W_hh, W_out, latent, W_lat, b_lat,
                     Wih_s, Whh_s, Wout_s, h_f32, h_s);
  for (int t=0; t<T_; ++t){
    hipLaunchKernelGGL(gates_k, dim3(48), dim3(512), 0, stream,
                       t, emb, b_ih, b_hh, Wih_s, Whh_s, h_f32, h_s, slots);
    hipLaunchKernelGGL(pred_k, dim3(256), dim3(512), 0, stream,
                       t, Wout_s, h_s, b_out, out, slots);
  }
}